// Round 2
// baseline (489.484 us; speedup 1.0000x reference)
//
#include <hip/hip_runtime.h>
#include <math.h>

#define NN 50000
#define EE 800000
#define DIN 256
#define NEG_SLOPE 0.01f

typedef __attribute__((ext_vector_type(8))) short bf16x8;
typedef __attribute__((ext_vector_type(8))) unsigned short u16x8;
typedef __attribute__((ext_vector_type(4))) float f32x4;
typedef __attribute__((ext_vector_type(4))) _Float16 f16x4;

__device__ __forceinline__ unsigned short bf16_rne(float f) {
    unsigned int u = __float_as_uint(f);
    u += 0x7fffu + ((u >> 16) & 1u);
    return (unsigned short)(u >> 16);
}
__device__ __forceinline__ float bf16_tof(unsigned short h) {
    return __uint_as_float(((unsigned int)h) << 16);
}

// ---------------------------------------------------------------------------
// CSR build. histrank: count + per-edge rank (atomic off the scatter path).
// ---------------------------------------------------------------------------
__global__ __launch_bounds__(256) void histrank_kernel(const int* __restrict__ dst,
                                                       int* __restrict__ cnt,
                                                       int* __restrict__ pos, int E) {
    int e = blockIdx.x * 256 + threadIdx.x;
    if (e < E) pos[e] = atomicAdd(&cnt[dst[e]], 1);
}

__global__ __launch_bounds__(1024) void scanA_kernel(const int* __restrict__ cnt,
                                                     int* __restrict__ off,
                                                     int* __restrict__ aux, int Nn) {
    __shared__ int wsums[16];
    int tid = threadIdx.x, lane = tid & 63, w = tid >> 6;
    int i = blockIdx.x * 1024 + tid;
    int v = (i < Nn) ? cnt[i] : 0;
    int x = v;
#pragma unroll
    for (int d = 1; d < 64; d <<= 1) {
        int y = __shfl_up(x, d);
        if (lane >= d) x += y;
    }
    if (lane == 63) wsums[w] = x;
    __syncthreads();
    if (w == 0 && lane < 16) {
        int ws = wsums[lane];
#pragma unroll
        for (int d = 1; d < 16; d <<= 1) {
            int y = __shfl_up(ws, d);
            if (lane >= d) ws += y;
        }
        wsums[lane] = ws;
    }
    __syncthreads();
    int incl = x + (w > 0 ? wsums[w - 1] : 0);
    if (i < Nn) off[i + 1] = incl;
    if (tid == 1023) aux[blockIdx.x] = incl;
}

__global__ __launch_bounds__(1024) void scanC_kernel(const int* __restrict__ aux,
                                                     int* __restrict__ off, int Nn) {
    int b = blockIdx.x;
    int prefix = 0;
    for (int j = 0; j < b; j++) prefix += aux[j];
    int i = b * 1024 + threadIdx.x;
    if (i < Nn) off[i + 1] += prefix;
    if (i == 0 && b == 0) off[0] = 0;
}

__global__ __launch_bounds__(256) void scatter_kernel(const int* __restrict__ src,
                                                      const int* __restrict__ dst,
                                                      const int* __restrict__ off,
                                                      const int* __restrict__ pos,
                                                      int* __restrict__ esrc, int E) {
    int e = blockIdx.x * 256 + threadIdx.x;
    if (e >= E) return;
    int d = dst[e];
    esrc[off[d] + pos[e]] = src[e];
}

// ---------------------------------------------------------------------------
// One-shot weight convert + transpose: W[H][D][64] -> Wt hi/lo [H*64][D]
// ---------------------------------------------------------------------------
__global__ __launch_bounds__(256) void conv_w_kernel(
    const float* __restrict__ W0, const float* __restrict__ W1,
    const float* __restrict__ Wf, unsigned short* __restrict__ w0h,
    unsigned short* __restrict__ w0l, unsigned short* __restrict__ w1h,
    unsigned short* __restrict__ w1l, unsigned short* __restrict__ wfh,
    unsigned short* __restrict__ wfl) {
    int t = blockIdx.x * 256 + threadIdx.x;
    const float* W;
    unsigned short *oh, *ol;
    int D, u;
    if (t < 32768) { W = W0; oh = w0h; ol = w0l; D = 256; u = t; }
    else if (t < 49152) { W = W1; oh = w1h; ol = w1l; D = 128; u = t - 32768; }
    else if (t < 57344) { W = Wf; oh = wfh; ol = wfl; D = 128; u = t - 49152; }
    else return;
    int d = u & (D - 1);
    int n = u / D;
    float v = W[((size_t)(n >> 6) * D + d) * 64 + (n & 63)];
    unsigned short hi = bf16_rne(v);
    unsigned short lo = bf16_rne(v - bf16_tof(hi));
    oh[(size_t)n * D + d] = hi;
    ol[(size_t)n * D + d] = lo;
}

// ---------------------------------------------------------------------------
// MFMA bf16x3 GEMM + fused attention dots. FT written as fp16 (gather dtype).
// ---------------------------------------------------------------------------
#define LDK 40

template <int NCOL, bool AFP32>
__global__ __launch_bounds__(256) void gemm_attn(
    const float* __restrict__ Xf, const unsigned short* __restrict__ Xhi,
    const unsigned short* __restrict__ Xlo, const unsigned short* __restrict__ Wthi,
    const unsigned short* __restrict__ Wtlo, const float* __restrict__ bias,
    const float* __restrict__ al, const float* __restrict__ bl,
    const float* __restrict__ ar, const float* __restrict__ br,
    _Float16* __restrict__ FT, float* __restrict__ A1, float* __restrict__ A2,
    int Nn, int D) {
    const int H = NCOL / 64;
    const int NC16 = NCOL / 16;
    __shared__ __align__(16) unsigned short Ahi_s[64 * LDK];
    __shared__ __align__(16) unsigned short Alo_s[64 * LDK];
    __shared__ __align__(16) unsigned short Bhi_s[NCOL * LDK];
    __shared__ __align__(16) unsigned short Blo_s[NCOL * LDK];

    int tid = threadIdx.x;
    int wv = tid >> 6, l = tid & 63, lm = l & 15, quad = l >> 4;
    int m0 = blockIdx.x * 64;

    f32x4 acc[NC16];
#pragma unroll
    for (int c = 0; c < NC16; c++) acc[c] = (f32x4){0.f, 0.f, 0.f, 0.f};

    for (int d0 = 0; d0 < D; d0 += 32) {
        if (AFP32) {
#pragma unroll
            for (int i = 0; i < 2; i++) {
                int u = tid + i * 256;
                int row = u >> 3, c4 = u & 7;
                float4 v = make_float4(0.f, 0.f, 0.f, 0.f);
                if (m0 + row < Nn)
                    v = *(const float4*)&Xf[(size_t)(m0 + row) * D + d0 + c4 * 4];
                float f[4] = {v.x, v.y, v.z, v.w};
                unsigned short hi[4], lo[4];
#pragma unroll
                for (int j = 0; j < 4; j++) {
                    hi[j] = bf16_rne(f[j]);
                    lo[j] = bf16_rne(f[j] - bf16_tof(hi[j]));
                }
                *(ushort4*)&Ahi_s[row * LDK + c4 * 4] = make_ushort4(hi[0], hi[1], hi[2], hi[3]);
                *(ushort4*)&Alo_s[row * LDK + c4 * 4] = make_ushort4(lo[0], lo[1], lo[2], lo[3]);
            }
        } else {
            int row = tid >> 2, q = tid & 3;
            u16x8 vh = (u16x8)0, vl = (u16x8)0;
            if (m0 + row < Nn) {
                vh = *(const u16x8*)&Xhi[(size_t)(m0 + row) * D + d0 + q * 8];
                vl = *(const u16x8*)&Xlo[(size_t)(m0 + row) * D + d0 + q * 8];
            }
            *(u16x8*)&Ahi_s[row * LDK + q * 8] = vh;
            *(u16x8*)&Alo_s[row * LDK + q * 8] = vl;
        }
#pragma unroll
        for (int i = 0; i < NCOL / 64; i++) {
            int u = tid + i * 256;
            int n = u >> 2, q = u & 3;
            *(u16x8*)&Bhi_s[n * LDK + q * 8] =
                *(const u16x8*)&Wthi[(size_t)n * D + d0 + q * 8];
            *(u16x8*)&Blo_s[n * LDK + q * 8] =
                *(const u16x8*)&Wtlo[(size_t)n * D + d0 + q * 8];
        }
        __syncthreads();

        int arow = wv * 16 + lm;
        bf16x8 ah = *(const bf16x8*)&Ahi_s[arow * LDK + quad * 8];
        bf16x8 alo = *(const bf16x8*)&Alo_s[arow * LDK + quad * 8];
#pragma unroll
        for (int c = 0; c < NC16; c++) {
            bf16x8 bh = *(const bf16x8*)&Bhi_s[(c * 16 + lm) * LDK + quad * 8];
            bf16x8 blo = *(const bf16x8*)&Blo_s[(c * 16 + lm) * LDK + quad * 8];
            acc[c] = __builtin_amdgcn_mfma_f32_16x16x32_bf16(ah, bh, acc[c], 0, 0, 0);
            acc[c] = __builtin_amdgcn_mfma_f32_16x16x32_bf16(ah, blo, acc[c], 0, 0, 0);
            acc[c] = __builtin_amdgcn_mfma_f32_16x16x32_bf16(alo, bh, acc[c], 0, 0, 0);
        }
        __syncthreads();
    }

    float bj[NC16], alj[NC16], arj[NC16];
#pragma unroll
    for (int c = 0; c < NC16; c++) {
        bj[c] = bias[c * 16 + lm];
        alj[c] = al[c * 16 + lm];
        arj[c] = ar[c * 16 + lm];
    }
#pragma unroll
    for (int reg = 0; reg < 4; reg++) {
        int row = m0 + wv * 16 + quad * 4 + reg;
        bool ok = row < Nn;
        float s1[H], s2[H];
#pragma unroll
        for (int h = 0; h < H; h++) { s1[h] = 0.f; s2[h] = 0.f; }
#pragma unroll
        for (int c = 0; c < NC16; c++) {
            float o = acc[c][reg] + bj[c];
            int h = c >> 2;
            s1[h] += o * alj[c];
            s2[h] += o * arj[c];
            if (ok) FT[(size_t)row * NCOL + c * 16 + lm] = (_Float16)o;
        }
#pragma unroll
        for (int h = 0; h < H; h++) {
#pragma unroll
            for (int d = 1; d < 16; d <<= 1) {
                s1[h] += __shfl_xor(s1[h], d);
                s2[h] += __shfl_xor(s2[h], d);
            }
        }
        if (ok && lm == 0) {
#pragma unroll
            for (int h = 0; h < H; h++) {
                A1[(size_t)row * H + h] = s1[h] + bl[h];
                A2[(size_t)row * H + h] = s2[h] + br[h];
            }
        }
    }
}

// ---------------------------------------------------------------------------
// Edge-weight pass (H=2): one wave per dst node. Computes w = exp(leakyrelu)
// once, packs {src, w} per head (coalesced 8B streams for the slice kernels),
// and 1/denom per node+head. Inline scores are exp-safe in fp32 (O(+-10)).
// ---------------------------------------------------------------------------
__global__ __launch_bounds__(256) void wgt2_kernel(
    const float* __restrict__ a1, const float* __restrict__ a2,
    const int* __restrict__ off, const int* __restrict__ esrc,
    int2* __restrict__ pk0, int2* __restrict__ pk1, float* __restrict__ rd,
    int Nn) {
    int wv = threadIdx.x >> 6, lane = threadIdx.x & 63;
    int n = blockIdx.x * 4 + wv;
    if (n >= Nn) return;
    int o0 = off[n], deg = off[n + 1] - o0;
    if (deg == 0) return;
    float2 a1v = *(const float2*)&a1[(size_t)n * 2];
    float ds0 = 0.f, ds1 = 0.f;
    for (int e0 = 0; e0 < deg; e0 += 64) {
        if (e0 + lane < deg) {
            int sj = esrc[o0 + e0 + lane];
            float2 a2j = *(const float2*)&a2[(size_t)sj * 2];
            float t0 = a1v.x + a2j.x;
            float t1 = a1v.y + a2j.y;
            t0 = t0 > 0.f ? t0 : NEG_SLOPE * t0;
            t1 = t1 > 0.f ? t1 : NEG_SLOPE * t1;
            float w0 = __expf(t0);
            float w1 = __expf(t1);
            ds0 += w0;
            ds1 += w1;
            pk0[o0 + e0 + lane] = make_int2(sj, __float_as_int(w0));
            pk1[o0 + e0 + lane] = make_int2(sj, __float_as_int(w1));
        }
    }
#pragma unroll
    for (int d = 1; d < 64; d <<= 1) {
        ds0 += __shfl_xor(ds0, d);
        ds1 += __shfl_xor(ds1, d);
    }
    if (lane == 0) *(float2*)&rd[(size_t)n * 2] = make_float2(1.f / ds0, 1.f / ds1);
}

// H=1 variant: a1/a2 are [N], single packed stream + scalar 1/denom.
__global__ __launch_bounds__(256) void wgtf_kernel(
    const float* __restrict__ a1, const float* __restrict__ a2,
    const int* __restrict__ off, const int* __restrict__ esrc,
    int2* __restrict__ pk, float* __restrict__ rd, int Nn) {
    int wv = threadIdx.x >> 6, lane = threadIdx.x & 63;
    int n = blockIdx.x * 4 + wv;
    if (n >= Nn) return;
    int o0 = off[n], deg = off[n + 1] - o0;
    if (deg == 0) return;
    float a1v = a1[n];
    float ds = 0.f;
    for (int e0 = 0; e0 < deg; e0 += 64) {
        if (e0 + lane < deg) {
            int sj = esrc[o0 + e0 + lane];
            float t = a1v + a2[sj];
            t = t > 0.f ? t : NEG_SLOPE * t;
            float w = __expf(t);
            ds += w;
            pk[o0 + e0 + lane] = make_int2(sj, __float_as_int(w));
        }
    }
#pragma unroll
    for (int d = 1; d < 64; d <<= 1) ds += __shfl_xor(ds, d);
    if (lane == 0) rd[n] = 1.f / ds;
}

// ---------------------------------------------------------------------------
// Sliced gather-accumulate (H=2): grid = 4 slices x node-chunks, slice in the
// LOW 2 bits of blockIdx so slice s is pinned to XCDs {s, s+4} (blockIdx%8 ->
// XCD round-robin). Slice footprint = 50000*32*2B = 3.2 MB < 4 MB L2, so the
// random row-gathers become L2 hits. 8 edges/wave-iter, 8 lanes x f16x4 each.
// Pad entries carry w=0 (exact no-op). Output bf16 hi/lo for the next GEMM.
// ---------------------------------------------------------------------------
__global__ __launch_bounds__(256) void sagg2_kernel(
    const _Float16* __restrict__ ft, const int2* __restrict__ pk0,
    const int2* __restrict__ pk1, const float* __restrict__ rd,
    const int* __restrict__ off, unsigned short* __restrict__ ohi,
    unsigned short* __restrict__ olo, int Nn) {
    __shared__ __align__(16) int2 pks[4][64];
    int wv = threadIdx.x >> 6, lane = threadIdx.x & 63;
    int s = blockIdx.x & 3;
    int n = (blockIdx.x >> 2) * 4 + wv;
    if (n >= Nn) return;
    int g = lane >> 3;            // edge within octet
    int el = (lane & 7) * 4;      // elem within slice
    int col = s * 32 + el;
    int o0 = off[n], deg = off[n + 1] - o0;
    if (deg == 0) {
        if (lane < 8) {
            *(ushort4*)&ohi[(size_t)n * 128 + col] = make_ushort4(0, 0, 0, 0);
            *(ushort4*)&olo[(size_t)n * 128 + col] = make_ushort4(0, 0, 0, 0);
        }
        return;
    }
    const int2* __restrict__ pk = (s >> 1) ? pk1 : pk0;
    float ac0 = 0.f, ac1 = 0.f, ac2 = 0.f, ac3 = 0.f;
    for (int e0 = 0; e0 < deg; e0 += 64) {
        int nE = min(64, deg - e0);
        int2 p = make_int2(0, 0);  // w = 0 pad
        if (lane < nE) p = pk[o0 + e0 + lane];
        pks[wv][lane] = p;
        // wave-synchronous: DS ops within a wave execute in order, no barrier.
        int noct = (nE + 7) >> 3;
        int q = 0;
        for (; q + 2 <= noct; q += 2) {
            int2 pa = pks[wv][q * 8 + g];
            int2 pb = pks[wv][q * 8 + 8 + g];
            f16x4 fa = *(const f16x4*)&ft[(size_t)pa.x * 128 + col];
            f16x4 fb = *(const f16x4*)&ft[(size_t)pb.x * 128 + col];
            float wa = __int_as_float(pa.y), wb = __int_as_float(pb.y);
            ac0 += wa * (float)fa.x;
            ac1 += wa * (float)fa.y;
            ac2 += wa * (float)fa.z;
            ac3 += wa * (float)fa.w;
            ac0 += wb * (float)fb.x;
            ac1 += wb * (float)fb.y;
            ac2 += wb * (float)fb.z;
            ac3 += wb * (float)fb.w;
        }
        for (; q < noct; q++) {
            int2 pa = pks[wv][q * 8 + g];
            f16x4 fa = *(const f16x4*)&ft[(size_t)pa.x * 128 + col];
            float wa = __int_as_float(pa.y);
            ac0 += wa * (float)fa.x;
            ac1 += wa * (float)fa.y;
            ac2 += wa * (float)fa.z;
            ac3 += wa * (float)fa.w;
        }
    }
    // combine the 8 edge-groups' partials (lane bits 3,4,5)
    ac0 += __shfl_xor(ac0, 8);
    ac1 += __shfl_xor(ac1, 8);
    ac2 += __shfl_xor(ac2, 8);
    ac3 += __shfl_xor(ac3, 8);
    ac0 += __shfl_xor(ac0, 16);
    ac1 += __shfl_xor(ac1, 16);
    ac2 += __shfl_xor(ac2, 16);
    ac3 += __shfl_xor(ac3, 16);
    ac0 += __shfl_xor(ac0, 32);
    ac1 += __shfl_xor(ac1, 32);
    ac2 += __shfl_xor(ac2, 32);
    ac3 += __shfl_xor(ac3, 32);
    if (lane < 8) {
        float rdv = rd[(size_t)n * 2 + (s >> 1)];
        float r[4] = {ac0 * rdv, ac1 * rdv, ac2 * rdv, ac3 * rdv};
        unsigned short rh[4], rl[4];
#pragma unroll
        for (int u = 0; u < 4; u++) {
            float v = r[u] > 0.f ? r[u] : expm1f(r[u]);
            rh[u] = bf16_rne(v);
            rl[u] = bf16_rne(v - bf16_tof(rh[u]));
        }
        *(ushort4*)&ohi[(size_t)n * 128 + col] = make_ushort4(rh[0], rh[1], rh[2], rh[3]);
        *(ushort4*)&olo[(size_t)n * 128 + col] = make_ushort4(rl[0], rl[1], rl[2], rl[3]);
    }
}

// H=1 variant: 2 slices of 32 elems (slice in LOW bit -> XCDs {s,s+2,s+4,s+6},
// footprint 3.2 MB each), ft rows 64 elems, fp32 output (d_out).
__global__ __launch_bounds__(256) void saggf_kernel(
    const _Float16* __restrict__ ft, const int2* __restrict__ pk,
    const float* __restrict__ rd, const int* __restrict__ off,
    float* __restrict__ out, int Nn) {
    __shared__ __align__(16) int2 pks[4][64];
    int wv = threadIdx.x >> 6, lane = threadIdx.x & 63;
    int s = blockIdx.x & 1;
    int n = (blockIdx.x >> 1) * 4 + wv;
    if (n >= Nn) return;
    int g = lane >> 3;
    int el = (lane & 7) * 4;
    int col = s * 32 + el;
    int o0 = off[n], deg = off[n + 1] - o0;
    if (deg == 0) {
        if (lane < 8) *(float4*)&out[(size_t)n * 64 + col] = make_float4(0.f, 0.f, 0.f, 0.f);
        return;
    }
    float ac0 = 0.f, ac1 = 0.f, ac2 = 0.f, ac3 = 0.f;
    for (int e0 = 0; e0 < deg; e0 += 64) {
        int nE = min(64, deg - e0);
        int2 p = make_int2(0, 0);
        if (lane < nE) p = pk[o0 + e0 + lane];
        pks[wv][lane] = p;
        int noct = (nE + 7) >> 3;
        int q = 0;
        for (; q + 2 <= noct; q += 2) {
            int2 pa = pks[wv][q * 8 + g];
            int2 pb = pks[wv][q * 8 + 8 + g];
            f16x4 fa = *(const f16x4*)&ft[(size_t)pa.x * 64 + col];
            f16x4 fb = *(const f16x4*)&ft[(size_t)pb.x * 64 + col];
            float wa = __int_as_float(pa.y), wb = __int_as_float(pb.y);
            ac0 += wa * (float)fa.x;
            ac1 += wa * (float)fa.y;
            ac2 += wa * (float)fa.z;
            ac3 += wa * (float)fa.w;
            ac0 += wb * (float)fb.x;
            ac1 += wb * (float)fb.y;
            ac2 += wb * (float)fb.z;
            ac3 += wb * (float)fb.w;
        }
        for (; q < noct; q++) {
            int2 pa = pks[wv][q * 8 + g];
            f16x4 fa = *(const f16x4*)&ft[(size_t)pa.x * 64 + col];
            float wa = __int_as_float(pa.y);
            ac0 += wa * (float)fa.x;
            ac1 += wa * (float)fa.y;
            ac2 += wa * (float)fa.z;
            ac3 += wa * (float)fa.w;
        }
    }
    ac0 += __shfl_xor(ac0, 8);
    ac1 += __shfl_xor(ac1, 8);
    ac2 += __shfl_xor(ac2, 8);
    ac3 += __shfl_xor(ac3, 8);
    ac0 += __shfl_xor(ac0, 16);
    ac1 += __shfl_xor(ac1, 16);
    ac2 += __shfl_xor(ac2, 16);
    ac3 += __shfl_xor(ac3, 16);
    ac0 += __shfl_xor(ac0, 32);
    ac1 += __shfl_xor(ac1, 32);
    ac2 += __shfl_xor(ac2, 32);
    ac3 += __shfl_xor(ac3, 32);
    if (lane < 8) {
        float rdv = rd[n];
        float r[4] = {ac0 * rdv, ac1 * rdv, ac2 * rdv, ac3 * rdv};
#pragma unroll
        for (int u = 0; u < 4; u++) r[u] = r[u] > 0.f ? r[u] : expm1f(r[u]);
        *(float4*)&out[(size_t)n * 64 + col] = make_float4(r[0], r[1], r[2], r[3]);
    }
}

// ---------------------------------------------------------------------------
// launch
// ---------------------------------------------------------------------------
extern "C" void kernel_launch(void* const* d_in, const int* in_sizes, int n_in,
                              void* d_out, int out_size, void* d_ws, size_t ws_size,
                              hipStream_t stream) {
    const float* features = (const float*)d_in[0];
    const int* src = (const int*)d_in[1];
    const int* dst = (const int*)d_in[2];
    const float* W0 = (const float*)d_in[3];
    const float* b0 = (const float*)d_in[4];
    const float* al0 = (const float*)d_in[5];
    const float* bl0 = (const float*)d_in[6];
    const float* ar0 = (const float*)d_in[7];
    const float* br0 = (const float*)d_in[8];
    const float* W1 = (const float*)d_in[9];
    const float* b1 = (const float*)d_in[10];
    const float* al1 = (const float*)d_in[11];
    const float* bl1 = (const float*)d_in[12];
    const float* ar1 = (const float*)d_in[13];
    const float* br1 = (const float*)d_in[14];
    const float* Wf = (const float*)d_in[15];
    const float* bf = (const float*)d_in[16];
    const float* alf = (const float*)d_in[17];
    const float* blf = (const float*)d_in[18];
    const float* arf = (const float*)d_in[19];
    const float* brf = (const float*)d_in[20];

    char* p = (char*)d_ws;
    auto carve = [&](size_t bytes) {
        void* q = (void*)p;
        p += (bytes + 255) & ~(size_t)255;
        return q;
    };
    _Float16* ft = (_Float16*)carve((size_t)NN * 128 * 2);
    unsigned short* Xhi = (unsigned short*)carve((size_t)NN * 128 * 2);
    unsigned short* Xlo = (unsigned short*)carve((size_t)NN * 128 * 2);
    float* a1 = (float*)carve((size_t)NN * 2 * 4);
    float* a2 = (float*)carve((size_t)NN * 2 * 4);
    float* rd = (float*)carve((size_t)NN * 2 * 4);
    int* off = (int*)carve((size_t)(NN + 1) * 4);
    int* cnt = (int*)carve((size_t)NN * 4);
    int* esrc = (int*)carve((size_t)EE * 4);
    int* pos = (int*)carve((size_t)EE * 4);
    int2* pk0 = (int2*)carve((size_t)EE * 8);
    int2* pk1 = (int2*)carve((size_t)EE * 8);
    int* aux = (int*)carve(64 * 4);
    unsigned short* w0h = (unsigned short*)carve(32768 * 2);
    unsigned short* w0l = (unsigned short*)carve(32768 * 2);
    unsigned short* w1h = (unsigned short*)carve(16384 * 2);
    unsigned short* w1l = (unsigned short*)carve(16384 * 2);
    unsigned short* wfh = (unsigned short*)carve(8192 * 2);
    unsigned short* wfl = (unsigned short*)carve(8192 * 2);

    const int NB_SCAN = (NN + 1023) / 1024;
    const int GE = (EE + 255) / 256;

    // ---- CSR build + weight convert ----
    hipMemsetAsync(cnt, 0, (size_t)NN * 4, stream);
    histrank_kernel<<<GE, 256, 0, stream>>>(dst, cnt, pos, EE);
    scanA_kernel<<<NB_SCAN, 1024, 0, stream>>>(cnt, off, aux, NN);
    scanC_kernel<<<NB_SCAN, 1024, 0, stream>>>(aux, off, NN);
    scatter_kernel<<<GE, 256, 0, stream>>>(src, dst, off, pos, esrc, EE);
    conv_w_kernel<<<(57344 + 255) / 256, 256, 0, stream>>>(W0, W1, Wf, w0h, w0l, w1h,
                                                           w1l, wfh, wfl);

    const int gx = (NN + 63) / 64;
    const int gn = (NN + 3) / 4;

    // ---- layer 0: D=256, H=2 (fp32 A) ----
    gemm_attn<128, true><<<gx, 256, 0, stream>>>(features, nullptr, nullptr, w0h, w0l,
                                                 b0, al0, bl0, ar0, br0, ft, a1, a2,
                                                 NN, DIN);
    wgt2_kernel<<<gn, 256, 0, stream>>>(a1, a2, off, esrc, pk0, pk1, rd, NN);
    sagg2_kernel<<<gn * 4, 256, 0, stream>>>(ft, pk0, pk1, rd, off, Xhi, Xlo, NN);

    // ---- layer 1: D=128, H=2 (bf16 A) ----
    gemm_attn<128, false><<<gx, 256, 0, stream>>>(nullptr, Xhi, Xlo, w1h, w1l, b1, al1,
                                                  bl1, ar1, br1, ft, a1, a2, NN, 128);
    wgt2_kernel<<<gn, 256, 0, stream>>>(a1, a2, off, esrc, pk0, pk1, rd, NN);
    sagg2_kernel<<<gn * 4, 256, 0, stream>>>(ft, pk0, pk1, rd, off, Xhi, Xlo, NN);

    // ---- final layer: D=128, H=1 ----
    gemm_attn<64, false><<<gx, 256, 0, stream>>>(nullptr, Xhi, Xlo, wfh, wfl, bf, alf,
                                                 blf, arf, brf, ft, a1, a2, NN, 128);
    wgtf_kernel<<<gn, 256, 0, stream>>>(a1, a2, off, esrc, pk0, rd, NN);
    saggf_kernel<<<gn * 2, 256, 0, stream>>>(ft, pk0, rd, off, (float*)d_out, NN);
}

// Round 3
// 335.035 us; speedup vs baseline: 1.4610x; 1.4610x over previous
//
#include <hip/hip_runtime.h>
#include <math.h>

#define NN 50000
#define EE 800000
#define DIN 256
#define NEG_SLOPE 0.01f

typedef __attribute__((ext_vector_type(8))) short bf16x8;
typedef __attribute__((ext_vector_type(8))) unsigned short u16x8;
typedef __attribute__((ext_vector_type(4))) float f32x4;
typedef __attribute__((ext_vector_type(2))) _Float16 f16x2;

__device__ __forceinline__ unsigned short bf16_rne(float f) {
    unsigned int u = __float_as_uint(f);
    u += 0x7fffu + ((u >> 16) & 1u);
    return (unsigned short)(u >> 16);
}
__device__ __forceinline__ float bf16_tof(unsigned short h) {
    return __uint_as_float(((unsigned int)h) << 16);
}

// ---------------------------------------------------------------------------
// CSR build. histrank: count + per-edge rank (atomic off the scatter path).
// ---------------------------------------------------------------------------
__global__ __launch_bounds__(256) void histrank_kernel(const int* __restrict__ dst,
                                                       int* __restrict__ cnt,
                                                       int* __restrict__ pos, int E) {
    int e = blockIdx.x * 256 + threadIdx.x;
    if (e < E) pos[e] = atomicAdd(&cnt[dst[e]], 1);
}

__global__ __launch_bounds__(1024) void scanA_kernel(const int* __restrict__ cnt,
                                                     int* __restrict__ off,
                                                     int* __restrict__ aux, int Nn) {
    __shared__ int wsums[16];
    int tid = threadIdx.x, lane = tid & 63, w = tid >> 6;
    int i = blockIdx.x * 1024 + tid;
    int v = (i < Nn) ? cnt[i] : 0;
    int x = v;
#pragma unroll
    for (int d = 1; d < 64; d <<= 1) {
        int y = __shfl_up(x, d);
        if (lane >= d) x += y;
    }
    if (lane == 63) wsums[w] = x;
    __syncthreads();
    if (w == 0 && lane < 16) {
        int ws = wsums[lane];
#pragma unroll
        for (int d = 1; d < 16; d <<= 1) {
            int y = __shfl_up(ws, d);
            if (lane >= d) ws += y;
        }
        wsums[lane] = ws;
    }
    __syncthreads();
    int incl = x + (w > 0 ? wsums[w - 1] : 0);
    if (i < Nn) off[i + 1] = incl;
    if (tid == 1023) aux[blockIdx.x] = incl;
}

__global__ __launch_bounds__(1024) void scanC_kernel(const int* __restrict__ aux,
                                                     int* __restrict__ off, int Nn) {
    int b = blockIdx.x;
    int prefix = 0;
    for (int j = 0; j < b; j++) prefix += aux[j];
    int i = b * 1024 + threadIdx.x;
    if (i < Nn) off[i + 1] += prefix;
    if (i == 0 && b == 0) off[0] = 0;
}

__global__ __launch_bounds__(256) void scatter_kernel(const int* __restrict__ src,
                                                      const int* __restrict__ dst,
                                                      const int* __restrict__ off,
                                                      const int* __restrict__ pos,
                                                      int* __restrict__ esrc, int E) {
    int e = blockIdx.x * 256 + threadIdx.x;
    if (e >= E) return;
    int d = dst[e];
    esrc[off[d] + pos[e]] = src[e];
}

// ---------------------------------------------------------------------------
// One-shot weight convert + transpose: W[H][D][64] -> Wt hi/lo [H*64][D]
// ---------------------------------------------------------------------------
__global__ __launch_bounds__(256) void conv_w_kernel(
    const float* __restrict__ W0, const float* __restrict__ W1,
    const float* __restrict__ Wf, unsigned short* __restrict__ w0h,
    unsigned short* __restrict__ w0l, unsigned short* __restrict__ w1h,
    unsigned short* __restrict__ w1l, unsigned short* __restrict__ wfh,
    unsigned short* __restrict__ wfl) {
    int t = blockIdx.x * 256 + threadIdx.x;
    const float* W;
    unsigned short *oh, *ol;
    int D, u;
    if (t < 32768) { W = W0; oh = w0h; ol = w0l; D = 256; u = t; }
    else if (t < 49152) { W = W1; oh = w1h; ol = w1l; D = 128; u = t - 32768; }
    else if (t < 57344) { W = Wf; oh = wfh; ol = wfl; D = 128; u = t - 49152; }
    else return;
    int d = u & (D - 1);
    int n = u / D;
    float v = W[((size_t)(n >> 6) * D + d) * 64 + (n & 63)];
    unsigned short hi = bf16_rne(v);
    unsigned short lo = bf16_rne(v - bf16_tof(hi));
    oh[(size_t)n * D + d] = hi;
    ol[(size_t)n * D + d] = lo;
}

// ---------------------------------------------------------------------------
// MFMA bf16x3 GEMM + fused attention dots. FT written as fp16 (gather dtype).
// MFMA issue is grouped by 4 columns, pass-major: same-accumulator MFMAs sit
// at dependency distance 4 (vs back-to-back before) -> no pipeline stalls.
// Per-acc pass order unchanged (hh, hl, lh per K-step) -> bitwise identical.
// ---------------------------------------------------------------------------
#define LDK 40

template <int NCOL, bool AFP32>
__global__ __launch_bounds__(256) void gemm_attn(
    const float* __restrict__ Xf, const unsigned short* __restrict__ Xhi,
    const unsigned short* __restrict__ Xlo, const unsigned short* __restrict__ Wthi,
    const unsigned short* __restrict__ Wtlo, const float* __restrict__ bias,
    const float* __restrict__ al, const float* __restrict__ bl,
    const float* __restrict__ ar, const float* __restrict__ br,
    _Float16* __restrict__ FT, float* __restrict__ A1, float* __restrict__ A2,
    int Nn, int D) {
    const int H = NCOL / 64;
    const int NC16 = NCOL / 16;
    __shared__ __align__(16) unsigned short Ahi_s[64 * LDK];
    __shared__ __align__(16) unsigned short Alo_s[64 * LDK];
    __shared__ __align__(16) unsigned short Bhi_s[NCOL * LDK];
    __shared__ __align__(16) unsigned short Blo_s[NCOL * LDK];

    int tid = threadIdx.x;
    int wv = tid >> 6, l = tid & 63, lm = l & 15, quad = l >> 4;
    int m0 = blockIdx.x * 64;

    f32x4 acc[NC16];
#pragma unroll
    for (int c = 0; c < NC16; c++) acc[c] = (f32x4){0.f, 0.f, 0.f, 0.f};

    for (int d0 = 0; d0 < D; d0 += 32) {
        if (AFP32) {
#pragma unroll
            for (int i = 0; i < 2; i++) {
                int u = tid + i * 256;
                int row = u >> 3, c4 = u & 7;
                float4 v = make_float4(0.f, 0.f, 0.f, 0.f);
                if (m0 + row < Nn)
                    v = *(const float4*)&Xf[(size_t)(m0 + row) * D + d0 + c4 * 4];
                float f[4] = {v.x, v.y, v.z, v.w};
                unsigned short hi[4], lo[4];
#pragma unroll
                for (int j = 0; j < 4; j++) {
                    hi[j] = bf16_rne(f[j]);
                    lo[j] = bf16_rne(f[j] - bf16_tof(hi[j]));
                }
                *(ushort4*)&Ahi_s[row * LDK + c4 * 4] = make_ushort4(hi[0], hi[1], hi[2], hi[3]);
                *(ushort4*)&Alo_s[row * LDK + c4 * 4] = make_ushort4(lo[0], lo[1], lo[2], lo[3]);
            }
        } else {
            int row = tid >> 2, q = tid & 3;
            u16x8 vh = (u16x8)0, vl = (u16x8)0;
            if (m0 + row < Nn) {
                vh = *(const u16x8*)&Xhi[(size_t)(m0 + row) * D + d0 + q * 8];
                vl = *(const u16x8*)&Xlo[(size_t)(m0 + row) * D + d0 + q * 8];
            }
            *(u16x8*)&Ahi_s[row * LDK + q * 8] = vh;
            *(u16x8*)&Alo_s[row * LDK + q * 8] = vl;
        }
#pragma unroll
        for (int i = 0; i < NCOL / 64; i++) {
            int u = tid + i * 256;
            int n = u >> 2, q = u & 3;
            *(u16x8*)&Bhi_s[n * LDK + q * 8] =
                *(const u16x8*)&Wthi[(size_t)n * D + d0 + q * 8];
            *(u16x8*)&Blo_s[n * LDK + q * 8] =
                *(const u16x8*)&Wtlo[(size_t)n * D + d0 + q * 8];
        }
        __syncthreads();

        int arow = wv * 16 + lm;
        bf16x8 ah = *(const bf16x8*)&Ahi_s[arow * LDK + quad * 8];
        bf16x8 alo = *(const bf16x8*)&Alo_s[arow * LDK + quad * 8];
#pragma unroll
        for (int cg = 0; cg < NC16; cg += 4) {
            bf16x8 bh4[4], bl4[4];
#pragma unroll
            for (int u = 0; u < 4; u++) {
                bh4[u] = *(const bf16x8*)&Bhi_s[((cg + u) * 16 + lm) * LDK + quad * 8];
                bl4[u] = *(const bf16x8*)&Blo_s[((cg + u) * 16 + lm) * LDK + quad * 8];
            }
#pragma unroll
            for (int u = 0; u < 4; u++)
                acc[cg + u] = __builtin_amdgcn_mfma_f32_16x16x32_bf16(ah, bh4[u], acc[cg + u], 0, 0, 0);
#pragma unroll
            for (int u = 0; u < 4; u++)
                acc[cg + u] = __builtin_amdgcn_mfma_f32_16x16x32_bf16(ah, bl4[u], acc[cg + u], 0, 0, 0);
#pragma unroll
            for (int u = 0; u < 4; u++)
                acc[cg + u] = __builtin_amdgcn_mfma_f32_16x16x32_bf16(alo, bh4[u], acc[cg + u], 0, 0, 0);
        }
        __syncthreads();
    }

    float bj[NC16], alj[NC16], arj[NC16];
#pragma unroll
    for (int c = 0; c < NC16; c++) {
        bj[c] = bias[c * 16 + lm];
        alj[c] = al[c * 16 + lm];
        arj[c] = ar[c * 16 + lm];
    }
#pragma unroll
    for (int reg = 0; reg < 4; reg++) {
        int row = m0 + wv * 16 + quad * 4 + reg;
        bool ok = row < Nn;
        float s1[H], s2[H];
#pragma unroll
        for (int h = 0; h < H; h++) { s1[h] = 0.f; s2[h] = 0.f; }
#pragma unroll
        for (int c = 0; c < NC16; c++) {
            float o = acc[c][reg] + bj[c];
            int h = c >> 2;
            s1[h] += o * alj[c];
            s2[h] += o * arj[c];
            if (ok) FT[(size_t)row * NCOL + c * 16 + lm] = (_Float16)o;
        }
#pragma unroll
        for (int h = 0; h < H; h++) {
#pragma unroll
            for (int d = 1; d < 16; d <<= 1) {
                s1[h] += __shfl_xor(s1[h], d);
                s2[h] += __shfl_xor(s2[h], d);
            }
        }
        if (ok && lm == 0) {
#pragma unroll
            for (int h = 0; h < H; h++) {
                A1[(size_t)row * H + h] = s1[h] + bl[h];
                A2[(size_t)row * H + h] = s2[h] + br[h];
            }
        }
    }
}

// ---------------------------------------------------------------------------
// Edge aggregation + ELU, one wave per dst node. Inline scores (no max:
// scores are O(+-10), exp safe in fp32; alpha identical to reference).
// ft gathered as fp16 (half the bytes of fp32). Gather loop batched 16-deep
// (16 outstanding loads/wave) with zero-weight padding -> no serial tail.
// H=2: lane owns ft elems 2*lane, 2*lane+1; bf16 hi/lo output for next GEMM.
// ---------------------------------------------------------------------------
__global__ __launch_bounds__(256) void agg2_kernel(
    const _Float16* __restrict__ ft, const float* __restrict__ a1,
    const float* __restrict__ a2, const int* __restrict__ off,
    const int* __restrict__ esrc, unsigned short* __restrict__ ohi,
    unsigned short* __restrict__ olo, int Nn) {
    __shared__ __align__(16) float ws[4][128];  // [wave][j*2 + h]
    __shared__ __align__(16) int sjs[4][64];
    int wv = threadIdx.x >> 6, lane = threadIdx.x & 63;
    int n = blockIdx.x * 4 + wv;
    if (n >= Nn) return;
    int o0 = off[n], deg = off[n + 1] - o0;
    int hs = lane >> 5, cl2 = lane * 2;
    if (deg == 0) {
        *(ushort2*)&ohi[(size_t)n * 128 + cl2] = make_ushort2(0, 0);
        *(ushort2*)&olo[(size_t)n * 128 + cl2] = make_ushort2(0, 0);
        return;
    }
    float2 a1v = *(const float2*)&a1[(size_t)n * 2];
    float ax = 0.f, ay = 0.f;
    float ds0 = 0.f, ds1 = 0.f;
    for (int e0 = 0; e0 < deg; e0 += 64) {
        int nE = min(64, deg - e0);
        float w0 = 0.f, w1 = 0.f;
        int sj = 0;
        if (lane < nE) {
            sj = esrc[o0 + e0 + lane];
            float2 a2j = *(const float2*)&a2[(size_t)sj * 2];
            float t0 = a1v.x + a2j.x;
            float t1 = a1v.y + a2j.y;
            t0 = t0 > 0.f ? t0 : NEG_SLOPE * t0;
            t1 = t1 > 0.f ? t1 : NEG_SLOPE * t1;
            w0 = __expf(t0);
            w1 = __expf(t1);
        }
        ds0 += w0;
        ds1 += w1;
        *(float2*)&ws[wv][lane * 2] = make_float2(w0, w1);
        sjs[wv][lane] = sj;
        // wave-synchronous: DS ops in a wave execute in order, no barrier.
        // Batch 16 edges per burst; slots >= nE carry w=0 (+0.0 no-op).
        int nB = (nE + 15) >> 4;
        for (int b = 0; b < nB; b++) {
            int j = b * 16;
            float wb[16];
            int sb[16];
#pragma unroll
            for (int u = 0; u < 16; u++) {
                wb[u] = ws[wv][(j + u) * 2 + hs];
                sb[u] = sjs[wv][j + u];
            }
            f16x2 f[16];
#pragma unroll
            for (int u = 0; u < 16; u++)
                f[u] = *(const f16x2*)&ft[(size_t)sb[u] * 128 + cl2];
#pragma unroll
            for (int u = 0; u < 16; u++) {
                ax += wb[u] * (float)f[u].x;
                ay += wb[u] * (float)f[u].y;
            }
        }
    }
#pragma unroll
    for (int d = 1; d < 64; d <<= 1) {
        ds0 += __shfl_xor(ds0, d);
        ds1 += __shfl_xor(ds1, d);
    }
    float rd = 1.f / (hs ? ds1 : ds0);
    float rx = ax * rd, ry = ay * rd;
    rx = rx > 0.f ? rx : expm1f(rx);
    ry = ry > 0.f ? ry : expm1f(ry);
    unsigned short hx = bf16_rne(rx), hy = bf16_rne(ry);
    unsigned short lx = bf16_rne(rx - bf16_tof(hx)), ly = bf16_rne(ry - bf16_tof(hy));
    *(ushort2*)&ohi[(size_t)n * 128 + cl2] = make_ushort2(hx, hy);
    *(ushort2*)&olo[(size_t)n * 128 + cl2] = make_ushort2(lx, ly);
}

// H=1: lane owns ft elem `lane` (fp16 gather); fp32 output (d_out).
__global__ __launch_bounds__(256) void agg1_kernel(
    const _Float16* __restrict__ ft, const float* __restrict__ a1,
    const float* __restrict__ a2, const int* __restrict__ off,
    const int* __restrict__ esrc, float* __restrict__ out, int Nn) {
    __shared__ __align__(16) float ws[4][64];
    __shared__ __align__(16) int sjs[4][64];
    int wv = threadIdx.x >> 6, lane = threadIdx.x & 63;
    int n = blockIdx.x * 4 + wv;
    if (n >= Nn) return;
    int o0 = off[n], deg = off[n + 1] - o0;
    if (deg == 0) {
        out[(size_t)n * 64 + lane] = 0.f;
        return;
    }
    float a1v = a1[n];
    float acc = 0.f, dsum = 0.f;
    for (int e0 = 0; e0 < deg; e0 += 64) {
        int nE = min(64, deg - e0);
        float wl = 0.f;
        int sj = 0;
        if (lane < nE) {
            sj = esrc[o0 + e0 + lane];
            float t = a1v + a2[sj];
            t = t > 0.f ? t : NEG_SLOPE * t;
            wl = __expf(t);
        }
        dsum += wl;
        ws[wv][lane] = wl;
        sjs[wv][lane] = sj;
        int nB = (nE + 15) >> 4;
        for (int b = 0; b < nB; b++) {
            int j = b * 16;
            float wb[16];
            int sb[16];
#pragma unroll
            for (int u = 0; u < 16; u++) {
                wb[u] = ws[wv][j + u];
                sb[u] = sjs[wv][j + u];
            }
            _Float16 f[16];
#pragma unroll
            for (int u = 0; u < 16; u++) f[u] = ft[(size_t)sb[u] * 64 + lane];
#pragma unroll
            for (int u = 0; u < 16; u++) acc += wb[u] * (float)f[u];
        }
    }
#pragma unroll
    for (int d = 1; d < 64; d <<= 1) dsum += __shfl_xor(dsum, d);
    float r = acc / dsum;
    out[(size_t)n * 64 + lane] = r > 0.f ? r : expm1f(r);
}

// ---------------------------------------------------------------------------
// launch
// ---------------------------------------------------------------------------
extern "C" void kernel_launch(void* const* d_in, const int* in_sizes, int n_in,
                              void* d_out, int out_size, void* d_ws, size_t ws_size,
                              hipStream_t stream) {
    const float* features = (const float*)d_in[0];
    const int* src = (const int*)d_in[1];
    const int* dst = (const int*)d_in[2];
    const float* W0 = (const float*)d_in[3];
    const float* b0 = (const float*)d_in[4];
    const float* al0 = (const float*)d_in[5];
    const float* bl0 = (const float*)d_in[6];
    const float* ar0 = (const float*)d_in[7];
    const float* br0 = (const float*)d_in[8];
    const float* W1 = (const float*)d_in[9];
    const float* b1 = (const float*)d_in[10];
    const float* al1 = (const float*)d_in[11];
    const float* bl1 = (const float*)d_in[12];
    const float* ar1 = (const float*)d_in[13];
    const float* br1 = (const float*)d_in[14];
    const float* Wf = (const float*)d_in[15];
    const float* bf = (const float*)d_in[16];
    const float* alf = (const float*)d_in[17];
    const float* blf = (const float*)d_in[18];
    const float* arf = (const float*)d_in[19];
    const float* brf = (const float*)d_in[20];

    char* p = (char*)d_ws;
    auto carve = [&](size_t bytes) {
        void* q = (void*)p;
        p += (bytes + 255) & ~(size_t)255;
        return q;
    };
    _Float16* ft = (_Float16*)carve((size_t)NN * 128 * 2);
    unsigned short* Xhi = (unsigned short*)carve((size_t)NN * 128 * 2);
    unsigned short* Xlo = (unsigned short*)carve((size_t)NN * 128 * 2);
    float* a1 = (float*)carve((size_t)NN * 2 * 4);
    float* a2 = (float*)carve((size_t)NN * 2 * 4);
    int* off = (int*)carve((size_t)(NN + 1) * 4);
    int* cnt = (int*)carve((size_t)NN * 4);
    int* esrc = (int*)carve((size_t)EE * 4);
    int* pos = (int*)carve((size_t)EE * 4);
    int* aux = (int*)carve(64 * 4);
    unsigned short* w0h = (unsigned short*)carve(32768 * 2);
    unsigned short* w0l = (unsigned short*)carve(32768 * 2);
    unsigned short* w1h = (unsigned short*)carve(16384 * 2);
    unsigned short* w1l = (unsigned short*)carve(16384 * 2);
    unsigned short* wfh = (unsigned short*)carve(8192 * 2);
    unsigned short* wfl = (unsigned short*)carve(8192 * 2);

    const int NB_SCAN = (NN + 1023) / 1024;
    const int GE = (EE + 255) / 256;

    // ---- CSR build + weight convert ----
    hipMemsetAsync(cnt, 0, (size_t)NN * 4, stream);
    histrank_kernel<<<GE, 256, 0, stream>>>(dst, cnt, pos, EE);
    scanA_kernel<<<NB_SCAN, 1024, 0, stream>>>(cnt, off, aux, NN);
    scanC_kernel<<<NB_SCAN, 1024, 0, stream>>>(aux, off, NN);
    scatter_kernel<<<GE, 256, 0, stream>>>(src, dst, off, pos, esrc, EE);
    conv_w_kernel<<<(57344 + 255) / 256, 256, 0, stream>>>(W0, W1, Wf, w0h, w0l, w1h,
                                                           w1l, wfh, wfl);

    const int gx = (NN + 63) / 64;
    const int gn = (NN + 3) / 4;

    // ---- layer 0: D=256, H=2 (fp32 A) ----
    gemm_attn<128, true><<<gx, 256, 0, stream>>>(features, nullptr, nullptr, w0h, w0l,
                                                 b0, al0, bl0, ar0, br0, ft, a1, a2,
                                                 NN, DIN);
    agg2_kernel<<<gn, 256, 0, stream>>>(ft, a1, a2, off, esrc, Xhi, Xlo, NN);

    // ---- layer 1: D=128, H=2 (bf16 A) ----
    gemm_attn<128, false><<<gx, 256, 0, stream>>>(nullptr, Xhi, Xlo, w1h, w1l, b1, al1,
                                                  bl1, ar1, br1, ft, a1, a2, NN, 128);
    agg2_kernel<<<gn, 256, 0, stream>>>(ft, a1, a2, off, esrc, Xhi, Xlo, NN);

    // ---- final layer: D=128, H=1 ----
    gemm_attn<64, false><<<gx, 256, 0, stream>>>(nullptr, Xhi, Xlo, wfh, wfl, bf, alf,
                                                 blf, arf, brf, ft, a1, a2, NN, 128);
    agg1_kernel<<<gn, 256, 0, stream>>>(ft, a1, a2, off, esrc, (float*)d_out, NN);
}

// Round 4
// 318.381 us; speedup vs baseline: 1.5374x; 1.0523x over previous
//
#include <hip/hip_runtime.h>
#include <math.h>

#define NN 50000
#define EE 800000
#define DIN 256
#define NEG_SLOPE 0.01f

typedef __attribute__((ext_vector_type(8))) short bf16x8;
typedef __attribute__((ext_vector_type(8))) unsigned short u16x8;
typedef __attribute__((ext_vector_type(4))) float f32x4;
typedef __attribute__((ext_vector_type(2))) _Float16 f16x2;

__device__ __forceinline__ unsigned short bf16_rne(float f) {
    unsigned int u = __float_as_uint(f);
    u += 0x7fffu + ((u >> 16) & 1u);
    return (unsigned short)(u >> 16);
}
__device__ __forceinline__ float bf16_tof(unsigned short h) {
    return __uint_as_float(((unsigned int)h) << 16);
}

// fp16-operand FMA with fp32 accumulate in ONE instruction (no v_cvt):
// D = f32(f16_half(S0)) * S1 + S2. Conversion is exact -> numerically
// identical to cvt+fma.
__device__ __forceinline__ void fmamix_lo(float& a, unsigned f, float w) {
    asm("v_fma_mix_f32 %0, %1, %2, %0 op_sel:[0,0,0] op_sel_hi:[1,0,0]"
        : "+v"(a)
        : "v"(f), "v"(w));
}
__device__ __forceinline__ void fmamix_hi(float& a, unsigned f, float w) {
    asm("v_fma_mix_f32 %0, %1, %2, %0 op_sel:[1,0,0] op_sel_hi:[1,0,0]"
        : "+v"(a)
        : "v"(f), "v"(w));
}

// ---------------------------------------------------------------------------
// CSR build. histrank: count + per-edge rank (atomic off the scatter path).
// ---------------------------------------------------------------------------
__global__ __launch_bounds__(256) void histrank_kernel(const int* __restrict__ dst,
                                                       int* __restrict__ cnt,
                                                       int* __restrict__ pos, int E) {
    int e = blockIdx.x * 256 + threadIdx.x;
    if (e < E) pos[e] = atomicAdd(&cnt[dst[e]], 1);
}

__global__ __launch_bounds__(1024) void scanA_kernel(const int* __restrict__ cnt,
                                                     int* __restrict__ off,
                                                     int* __restrict__ aux, int Nn) {
    __shared__ int wsums[16];
    int tid = threadIdx.x, lane = tid & 63, w = tid >> 6;
    int i = blockIdx.x * 1024 + tid;
    int v = (i < Nn) ? cnt[i] : 0;
    int x = v;
#pragma unroll
    for (int d = 1; d < 64; d <<= 1) {
        int y = __shfl_up(x, d);
        if (lane >= d) x += y;
    }
    if (lane == 63) wsums[w] = x;
    __syncthreads();
    if (w == 0 && lane < 16) {
        int ws = wsums[lane];
#pragma unroll
        for (int d = 1; d < 16; d <<= 1) {
            int y = __shfl_up(ws, d);
            if (lane >= d) ws += y;
        }
        wsums[lane] = ws;
    }
    __syncthreads();
    int incl = x + (w > 0 ? wsums[w - 1] : 0);
    if (i < Nn) off[i + 1] = incl;
    if (tid == 1023) aux[blockIdx.x] = incl;
}

__global__ __launch_bounds__(1024) void scanC_kernel(const int* __restrict__ aux,
                                                     int* __restrict__ off, int Nn) {
    int b = blockIdx.x;
    int prefix = 0;
    for (int j = 0; j < b; j++) prefix += aux[j];
    int i = b * 1024 + threadIdx.x;
    if (i < Nn) off[i + 1] += prefix;
    if (i == 0 && b == 0) off[0] = 0;
}

__global__ __launch_bounds__(256) void scatter_kernel(const int* __restrict__ src,
                                                      const int* __restrict__ dst,
                                                      const int* __restrict__ off,
                                                      const int* __restrict__ pos,
                                                      int* __restrict__ esrc, int E) {
    int e = blockIdx.x * 256 + threadIdx.x;
    if (e >= E) return;
    int d = dst[e];
    esrc[off[d] + pos[e]] = src[e];
}

// ---------------------------------------------------------------------------
// One-shot weight convert + transpose: W[H][D][64] -> Wt hi/lo [H*64][D]
// ---------------------------------------------------------------------------
__global__ __launch_bounds__(256) void conv_w_kernel(
    const float* __restrict__ W0, const float* __restrict__ W1,
    const float* __restrict__ Wf, unsigned short* __restrict__ w0h,
    unsigned short* __restrict__ w0l, unsigned short* __restrict__ w1h,
    unsigned short* __restrict__ w1l, unsigned short* __restrict__ wfh,
    unsigned short* __restrict__ wfl) {
    int t = blockIdx.x * 256 + threadIdx.x;
    const float* W;
    unsigned short *oh, *ol;
    int D, u;
    if (t < 32768) { W = W0; oh = w0h; ol = w0l; D = 256; u = t; }
    else if (t < 49152) { W = W1; oh = w1h; ol = w1l; D = 128; u = t - 32768; }
    else if (t < 57344) { W = Wf; oh = wfh; ol = wfl; D = 128; u = t - 49152; }
    else return;
    int d = u & (D - 1);
    int n = u / D;
    float v = W[((size_t)(n >> 6) * D + d) * 64 + (n & 63)];
    unsigned short hi = bf16_rne(v);
    unsigned short lo = bf16_rne(v - bf16_tof(hi));
    oh[(size_t)n * D + d] = hi;
    ol[(size_t)n * D + d] = lo;
}

// ---------------------------------------------------------------------------
// MFMA bf16x3 GEMM + fused attention dots. FT written as fp16 (gather dtype).
// MFMA issue grouped by 4 columns, pass-major (dep distance 4).
// ---------------------------------------------------------------------------
#define LDK 40

template <int NCOL, bool AFP32>
__global__ __launch_bounds__(256) void gemm_attn(
    const float* __restrict__ Xf, const unsigned short* __restrict__ Xhi,
    const unsigned short* __restrict__ Xlo, const unsigned short* __restrict__ Wthi,
    const unsigned short* __restrict__ Wtlo, const float* __restrict__ bias,
    const float* __restrict__ al, const float* __restrict__ bl,
    const float* __restrict__ ar, const float* __restrict__ br,
    _Float16* __restrict__ FT, float* __restrict__ A1, float* __restrict__ A2,
    int Nn, int D) {
    const int H = NCOL / 64;
    const int NC16 = NCOL / 16;
    __shared__ __align__(16) unsigned short Ahi_s[64 * LDK];
    __shared__ __align__(16) unsigned short Alo_s[64 * LDK];
    __shared__ __align__(16) unsigned short Bhi_s[NCOL * LDK];
    __shared__ __align__(16) unsigned short Blo_s[NCOL * LDK];

    int tid = threadIdx.x;
    int wv = tid >> 6, l = tid & 63, lm = l & 15, quad = l >> 4;
    int m0 = blockIdx.x * 64;

    f32x4 acc[NC16];
#pragma unroll
    for (int c = 0; c < NC16; c++) acc[c] = (f32x4){0.f, 0.f, 0.f, 0.f};

    for (int d0 = 0; d0 < D; d0 += 32) {
        if (AFP32) {
#pragma unroll
            for (int i = 0; i < 2; i++) {
                int u = tid + i * 256;
                int row = u >> 3, c4 = u & 7;
                float4 v = make_float4(0.f, 0.f, 0.f, 0.f);
                if (m0 + row < Nn)
                    v = *(const float4*)&Xf[(size_t)(m0 + row) * D + d0 + c4 * 4];
                float f[4] = {v.x, v.y, v.z, v.w};
                unsigned short hi[4], lo[4];
#pragma unroll
                for (int j = 0; j < 4; j++) {
                    hi[j] = bf16_rne(f[j]);
                    lo[j] = bf16_rne(f[j] - bf16_tof(hi[j]));
                }
                *(ushort4*)&Ahi_s[row * LDK + c4 * 4] = make_ushort4(hi[0], hi[1], hi[2], hi[3]);
                *(ushort4*)&Alo_s[row * LDK + c4 * 4] = make_ushort4(lo[0], lo[1], lo[2], lo[3]);
            }
        } else {
            int row = tid >> 2, q = tid & 3;
            u16x8 vh = (u16x8)0, vl = (u16x8)0;
            if (m0 + row < Nn) {
                vh = *(const u16x8*)&Xhi[(size_t)(m0 + row) * D + d0 + q * 8];
                vl = *(const u16x8*)&Xlo[(size_t)(m0 + row) * D + d0 + q * 8];
            }
            *(u16x8*)&Ahi_s[row * LDK + q * 8] = vh;
            *(u16x8*)&Alo_s[row * LDK + q * 8] = vl;
        }
#pragma unroll
        for (int i = 0; i < NCOL / 64; i++) {
            int u = tid + i * 256;
            int n = u >> 2, q = u & 3;
            *(u16x8*)&Bhi_s[n * LDK + q * 8] =
                *(const u16x8*)&Wthi[(size_t)n * D + d0 + q * 8];
            *(u16x8*)&Blo_s[n * LDK + q * 8] =
                *(const u16x8*)&Wtlo[(size_t)n * D + d0 + q * 8];
        }
        __syncthreads();

        int arow = wv * 16 + lm;
        bf16x8 ah = *(const bf16x8*)&Ahi_s[arow * LDK + quad * 8];
        bf16x8 alo = *(const bf16x8*)&Alo_s[arow * LDK + quad * 8];
#pragma unroll
        for (int cg = 0; cg < NC16; cg += 4) {
            bf16x8 bh4[4], bl4[4];
#pragma unroll
            for (int u = 0; u < 4; u++) {
                bh4[u] = *(const bf16x8*)&Bhi_s[((cg + u) * 16 + lm) * LDK + quad * 8];
                bl4[u] = *(const bf16x8*)&Blo_s[((cg + u) * 16 + lm) * LDK + quad * 8];
            }
#pragma unroll
            for (int u = 0; u < 4; u++)
                acc[cg + u] = __builtin_amdgcn_mfma_f32_16x16x32_bf16(ah, bh4[u], acc[cg + u], 0, 0, 0);
#pragma unroll
            for (int u = 0; u < 4; u++)
                acc[cg + u] = __builtin_amdgcn_mfma_f32_16x16x32_bf16(ah, bl4[u], acc[cg + u], 0, 0, 0);
#pragma unroll
            for (int u = 0; u < 4; u++)
                acc[cg + u] = __builtin_amdgcn_mfma_f32_16x16x32_bf16(alo, bh4[u], acc[cg + u], 0, 0, 0);
        }
        __syncthreads();
    }

    float bj[NC16], alj[NC16], arj[NC16];
#pragma unroll
    for (int c = 0; c < NC16; c++) {
        bj[c] = bias[c * 16 + lm];
        alj[c] = al[c * 16 + lm];
        arj[c] = ar[c * 16 + lm];
    }
#pragma unroll
    for (int reg = 0; reg < 4; reg++) {
        int row = m0 + wv * 16 + quad * 4 + reg;
        bool ok = row < Nn;
        float s1[H], s2[H];
#pragma unroll
        for (int h = 0; h < H; h++) { s1[h] = 0.f; s2[h] = 0.f; }
#pragma unroll
        for (int c = 0; c < NC16; c++) {
            float o = acc[c][reg] + bj[c];
            int h = c >> 2;
            s1[h] += o * alj[c];
            s2[h] += o * arj[c];
            if (ok) FT[(size_t)row * NCOL + c * 16 + lm] = (_Float16)o;
        }
#pragma unroll
        for (int h = 0; h < H; h++) {
#pragma unroll
            for (int d = 1; d < 16; d <<= 1) {
                s1[h] += __shfl_xor(s1[h], d);
                s2[h] += __shfl_xor(s2[h], d);
            }
        }
        if (ok && lm == 0) {
#pragma unroll
            for (int h = 0; h < H; h++) {
                A1[(size_t)row * H + h] = s1[h] + bl[h];
                A2[(size_t)row * H + h] = s2[h] + br[h];
            }
        }
    }
}

// ---------------------------------------------------------------------------
// Edge aggregation + ELU, one wave per dst node. Inline scores (no max:
// scores are O(+-10), exp safe in fp32; alpha identical to reference).
// Per-edge instruction diet: {sj,w} packed as int2 in LDS (1 ds_read_b64
// broadcast), 32-bit byte-offset gather addressing (SGPR base + 1
// v_lshl_add_u32), and v_fma_mix_f32 (no v_cvt). 16-deep batches, zero-
// weight padding (w=0 -> exact no-op).
// H=2: lane owns ft elems 2*lane, 2*lane+1; bf16 hi/lo output for next GEMM.
// ---------------------------------------------------------------------------
__global__ __launch_bounds__(256) void agg2_kernel(
    const _Float16* __restrict__ ft, const float* __restrict__ a1,
    const float* __restrict__ a2, const int* __restrict__ off,
    const int* __restrict__ esrc, unsigned short* __restrict__ ohi,
    unsigned short* __restrict__ olo, int Nn) {
    __shared__ __align__(16) int2 pk0s[4][64];
    __shared__ __align__(16) int2 pk1s[4][64];
    int wv = threadIdx.x >> 6, lane = threadIdx.x & 63;
    int n = blockIdx.x * 4 + wv;
    if (n >= Nn) return;
    int o0 = off[n], deg = off[n + 1] - o0;
    int hs = lane >> 5, cl2 = lane * 2;
    unsigned lb = (unsigned)lane * 4u;  // my byte offset within a 256B ft row
    if (deg == 0) {
        *(ushort2*)&ohi[(size_t)n * 128 + cl2] = make_ushort2(0, 0);
        *(ushort2*)&olo[(size_t)n * 128 + cl2] = make_ushort2(0, 0);
        return;
    }
    const char* ftb = (const char*)ft;
    const int2* pw = hs ? pk1s[wv] : pk0s[wv];
    float2 a1v = *(const float2*)&a1[(size_t)n * 2];
    float ax = 0.f, ay = 0.f;
    float ds0 = 0.f, ds1 = 0.f;
    for (int e0 = 0; e0 < deg; e0 += 64) {
        int nE = min(64, deg - e0);
        float w0 = 0.f, w1 = 0.f;
        int sj = 0;
        if (lane < nE) {
            sj = esrc[o0 + e0 + lane];
            float2 a2j = *(const float2*)((const char*)a2 + ((unsigned)sj << 3));
            float t0 = a1v.x + a2j.x;
            float t1 = a1v.y + a2j.y;
            t0 = t0 > 0.f ? t0 : NEG_SLOPE * t0;
            t1 = t1 > 0.f ? t1 : NEG_SLOPE * t1;
            w0 = __expf(t0);
            w1 = __expf(t1);
        }
        ds0 += w0;
        ds1 += w1;
        pk0s[wv][lane] = make_int2(sj, __float_as_int(w0));
        pk1s[wv][lane] = make_int2(sj, __float_as_int(w1));
        // wave-synchronous: DS ops in a wave execute in order, no barrier.
        // Slots >= nE carry w=0 (+0.0 no-op).
        int nB = (nE + 15) >> 4;
        for (int b = 0; b < nB; b++) {
            int j = b * 16;
            int2 pb[16];
#pragma unroll
            for (int u = 0; u < 16; u++) pb[u] = pw[j + u];
            unsigned f[16];
#pragma unroll
            for (int u = 0; u < 16; u++)
                f[u] = *(const unsigned*)(ftb + (((unsigned)pb[u].x << 8) + lb));
#pragma unroll
            for (int u = 0; u < 16; u++) {
                float w = __int_as_float(pb[u].y);
                fmamix_lo(ax, f[u], w);
                fmamix_hi(ay, f[u], w);
            }
        }
    }
#pragma unroll
    for (int d = 1; d < 64; d <<= 1) {
        ds0 += __shfl_xor(ds0, d);
        ds1 += __shfl_xor(ds1, d);
    }
    float rd = 1.f / (hs ? ds1 : ds0);
    float rx = ax * rd, ry = ay * rd;
    rx = rx > 0.f ? rx : expm1f(rx);
    ry = ry > 0.f ? ry : expm1f(ry);
    unsigned short hx = bf16_rne(rx), hy = bf16_rne(ry);
    unsigned short lx = bf16_rne(rx - bf16_tof(hx)), ly = bf16_rne(ry - bf16_tof(hy));
    *(ushort2*)&ohi[(size_t)n * 128 + cl2] = make_ushort2(hx, hy);
    *(ushort2*)&olo[(size_t)n * 128 + cl2] = make_ushort2(lx, ly);
}

// H=1: lane owns ft elem `lane` (fp16 gather, 128B rows); fp32 output.
__global__ __launch_bounds__(256) void agg1_kernel(
    const _Float16* __restrict__ ft, const float* __restrict__ a1,
    const float* __restrict__ a2, const int* __restrict__ off,
    const int* __restrict__ esrc, float* __restrict__ out, int Nn) {
    __shared__ __align__(16) int2 pks[4][64];
    int wv = threadIdx.x >> 6, lane = threadIdx.x & 63;
    int n = blockIdx.x * 4 + wv;
    if (n >= Nn) return;
    int o0 = off[n], deg = off[n + 1] - o0;
    if (deg == 0) {
        out[(size_t)n * 64 + lane] = 0.f;
        return;
    }
    const char* ftb = (const char*)ft;
    unsigned lb = (unsigned)lane * 2u;  // my byte offset within a 128B ft row
    float a1v = a1[n];
    float acc = 0.f, dsum = 0.f;
    for (int e0 = 0; e0 < deg; e0 += 64) {
        int nE = min(64, deg - e0);
        float wl = 0.f;
        int sj = 0;
        if (lane < nE) {
            sj = esrc[o0 + e0 + lane];
            float t = a1v + a2[sj];
            t = t > 0.f ? t : NEG_SLOPE * t;
            wl = __expf(t);
        }
        dsum += wl;
        pks[wv][lane] = make_int2(sj, __float_as_int(wl));
        int nB = (nE + 15) >> 4;
        for (int b = 0; b < nB; b++) {
            int j = b * 16;
            int2 pb[16];
#pragma unroll
            for (int u = 0; u < 16; u++) pb[u] = pks[wv][j + u];
            unsigned f[16];
#pragma unroll
            for (int u = 0; u < 16; u++)
                f[u] = *(const unsigned short*)(ftb + (((unsigned)pb[u].x << 7) + lb));
#pragma unroll
            for (int u = 0; u < 16; u++)
                fmamix_lo(acc, f[u], __int_as_float(pb[u].y));
        }
    }
#pragma unroll
    for (int d = 1; d < 64; d <<= 1) dsum += __shfl_xor(dsum, d);
    float r = acc / dsum;
    out[(size_t)n * 64 + lane] = r > 0.f ? r : expm1f(r);
}

// ---------------------------------------------------------------------------
// launch
// ---------------------------------------------------------------------------
extern "C" void kernel_launch(void* const* d_in, const int* in_sizes, int n_in,
                              void* d_out, int out_size, void* d_ws, size_t ws_size,
                              hipStream_t stream) {
    const float* features = (const float*)d_in[0];
    const int* src = (const int*)d_in[1];
    const int* dst = (const int*)d_in[2];
    const float* W0 = (const float*)d_in[3];
    const float* b0 = (const float*)d_in[4];
    const float* al0 = (const float*)d_in[5];
    const float* bl0 = (const float*)d_in[6];
    const float* ar0 = (const float*)d_in[7];
    const float* br0 = (const float*)d_in[8];
    const float* W1 = (const float*)d_in[9];
    const float* b1 = (const float*)d_in[10];
    const float* al1 = (const float*)d_in[11];
    const float* bl1 = (const float*)d_in[12];
    const float* ar1 = (const float*)d_in[13];
    const float* br1 = (const float*)d_in[14];
    const float* Wf = (const float*)d_in[15];
    const float* bf = (const float*)d_in[16];
    const float* alf = (const float*)d_in[17];
    const float* blf = (const float*)d_in[18];
    const float* arf = (const float*)d_in[19];
    const float* brf = (const float*)d_in[20];

    char* p = (char*)d_ws;
    auto carve = [&](size_t bytes) {
        void* q = (void*)p;
        p += (bytes + 255) & ~(size_t)255;
        return q;
    };
    _Float16* ft = (_Float16*)carve((size_t)NN * 128 * 2);
    unsigned short* Xhi = (unsigned short*)carve((size_t)NN * 128 * 2);
    unsigned short* Xlo = (unsigned short*)carve((size_t)NN * 128 * 2);
    float* a1 = (float*)carve((size_t)NN * 2 * 4);
    float* a2 = (float*)carve((size_t)NN * 2 * 4);
    int* off = (int*)carve((size_t)(NN + 1) * 4);
    int* cnt = (int*)carve((size_t)NN * 4);
    int* esrc = (int*)carve((size_t)EE * 4);
    int* pos = (int*)carve((size_t)EE * 4);
    int* aux = (int*)carve(64 * 4);
    unsigned short* w0h = (unsigned short*)carve(32768 * 2);
    unsigned short* w0l = (unsigned short*)carve(32768 * 2);
    unsigned short* w1h = (unsigned short*)carve(16384 * 2);
    unsigned short* w1l = (unsigned short*)carve(16384 * 2);
    unsigned short* wfh = (unsigned short*)carve(8192 * 2);
    unsigned short* wfl = (unsigned short*)carve(8192 * 2);

    const int NB_SCAN = (NN + 1023) / 1024;
    const int GE = (EE + 255) / 256;

    // ---- CSR build + weight convert ----
    hipMemsetAsync(cnt, 0, (size_t)NN * 4, stream);
    histrank_kernel<<<GE, 256, 0, stream>>>(dst, cnt, pos, EE);
    scanA_kernel<<<NB_SCAN, 1024, 0, stream>>>(cnt, off, aux, NN);
    scanC_kernel<<<NB_SCAN, 1024, 0, stream>>>(aux, off, NN);
    scatter_kernel<<<GE, 256, 0, stream>>>(src, dst, off, pos, esrc, EE);
    conv_w_kernel<<<(57344 + 255) / 256, 256, 0, stream>>>(W0, W1, Wf, w0h, w0l, w1h,
                                                           w1l, wfh, wfl);

    const int gx = (NN + 63) / 64;
    const int gn = (NN + 3) / 4;

    // ---- layer 0: D=256, H=2 (fp32 A) ----
    gemm_attn<128, true><<<gx, 256, 0, stream>>>(features, nullptr, nullptr, w0h, w0l,
                                                 b0, al0, bl0, ar0, br0, ft, a1, a2,
                                                 NN, DIN);
    agg2_kernel<<<gn, 256, 0, stream>>>(ft, a1, a2, off, esrc, Xhi, Xlo, NN);

    // ---- layer 1: D=128, H=2 (bf16 A) ----
    gemm_attn<128, false><<<gx, 256, 0, stream>>>(nullptr, Xhi, Xlo, w1h, w1l, b1, al1,
                                                  bl1, ar1, br1, ft, a1, a2, NN, 128);
    agg2_kernel<<<gn, 256, 0, stream>>>(ft, a1, a2, off, esrc, Xhi, Xlo, NN);

    // ---- final layer: D=128, H=1 ----
    gemm_attn<64, false><<<gx, 256, 0, stream>>>(nullptr, Xhi, Xlo, wfh, wfl, bf, alf,
                                                 blf, arf, brf, ft, a1, a2, NN, 128);
    agg1_kernel<<<gn, 256, 0, stream>>>(ft, a1, a2, off, esrc, (float*)d_out, NN);
}

// Round 5
// 301.625 us; speedup vs baseline: 1.6228x; 1.0556x over previous
//
#include <hip/hip_runtime.h>
#include <math.h>

#define NN 50000
#define EE 800000
#define DIN 256
#define NEG_SLOPE 0.01f

typedef __attribute__((ext_vector_type(8))) short bf16x8;
typedef __attribute__((ext_vector_type(8))) unsigned short u16x8;
typedef __attribute__((ext_vector_type(4))) float f32x4;
typedef __attribute__((ext_vector_type(2))) _Float16 f16x2;

__device__ __forceinline__ unsigned short bf16_rne(float f) {
    unsigned int u = __float_as_uint(f);
    u += 0x7fffu + ((u >> 16) & 1u);
    return (unsigned short)(u >> 16);
}
__device__ __forceinline__ float bf16_tof(unsigned short h) {
    return __uint_as_float(((unsigned int)h) << 16);
}

// fp16-operand FMA with fp32 accumulate in ONE instruction (no v_cvt):
// D = f32(f16_half(S0)) * S1 + S2. Conversion is exact -> numerically
// identical to cvt+fma.
__device__ __forceinline__ void fmamix_lo(float& a, unsigned f, float w) {
    asm("v_fma_mix_f32 %0, %1, %2, %0 op_sel:[0,0,0] op_sel_hi:[1,0,0]"
        : "+v"(a)
        : "v"(f), "v"(w));
}
__device__ __forceinline__ void fmamix_hi(float& a, unsigned f, float w) {
    asm("v_fma_mix_f32 %0, %1, %2, %0 op_sel:[1,0,0] op_sel_hi:[1,0,0]"
        : "+v"(a)
        : "v"(f), "v"(w));
}

// ---------------------------------------------------------------------------
// CSR build (scan + scatter; the histogram pass is fused into gemm0).
// ---------------------------------------------------------------------------
__global__ __launch_bounds__(1024) void scanA_kernel(const int* __restrict__ cnt,
                                                     int* __restrict__ off,
                                                     int* __restrict__ aux, int Nn) {
    __shared__ int wsums[16];
    int tid = threadIdx.x, lane = tid & 63, w = tid >> 6;
    int i = blockIdx.x * 1024 + tid;
    int v = (i < Nn) ? cnt[i] : 0;
    int x = v;
#pragma unroll
    for (int d = 1; d < 64; d <<= 1) {
        int y = __shfl_up(x, d);
        if (lane >= d) x += y;
    }
    if (lane == 63) wsums[w] = x;
    __syncthreads();
    if (w == 0 && lane < 16) {
        int ws = wsums[lane];
#pragma unroll
        for (int d = 1; d < 16; d <<= 1) {
            int y = __shfl_up(ws, d);
            if (lane >= d) ws += y;
        }
        wsums[lane] = ws;
    }
    __syncthreads();
    int incl = x + (w > 0 ? wsums[w - 1] : 0);
    if (i < Nn) off[i + 1] = incl;
    if (tid == 1023) aux[blockIdx.x] = incl;
}

__global__ __launch_bounds__(1024) void scanC_kernel(const int* __restrict__ aux,
                                                     int* __restrict__ off, int Nn) {
    int b = blockIdx.x;
    int prefix = 0;
    for (int j = 0; j < b; j++) prefix += aux[j];
    int i = b * 1024 + threadIdx.x;
    if (i < Nn) off[i + 1] += prefix;
    if (i == 0 && b == 0) off[0] = 0;
}

__global__ __launch_bounds__(256) void scatter_kernel(const int* __restrict__ src,
                                                      const int* __restrict__ dst,
                                                      const int* __restrict__ off,
                                                      const int* __restrict__ pos,
                                                      int* __restrict__ esrc, int E) {
    int e = blockIdx.x * 256 + threadIdx.x;
    if (e >= E) return;
    int d = dst[e];
    esrc[off[d] + pos[e]] = src[e];
}

// ---------------------------------------------------------------------------
// One-shot weight convert + transpose: W[H][D][64] -> Wt hi/lo [H*64][D]
// ---------------------------------------------------------------------------
__global__ __launch_bounds__(256) void conv_w_kernel(
    const float* __restrict__ W0, const float* __restrict__ W1,
    const float* __restrict__ Wf, unsigned short* __restrict__ w0h,
    unsigned short* __restrict__ w0l, unsigned short* __restrict__ w1h,
    unsigned short* __restrict__ w1l, unsigned short* __restrict__ wfh,
    unsigned short* __restrict__ wfl) {
    int t = blockIdx.x * 256 + threadIdx.x;
    const float* W;
    unsigned short *oh, *ol;
    int D, u;
    if (t < 32768) { W = W0; oh = w0h; ol = w0l; D = 256; u = t; }
    else if (t < 49152) { W = W1; oh = w1h; ol = w1l; D = 128; u = t - 32768; }
    else if (t < 57344) { W = Wf; oh = wfh; ol = wfl; D = 128; u = t - 49152; }
    else return;
    int d = u & (D - 1);
    int n = u / D;
    float v = W[((size_t)(n >> 6) * D + d) * 64 + (n & 63)];
    unsigned short hi = bf16_rne(v);
    unsigned short lo = bf16_rne(v - bf16_tof(hi));
    oh[(size_t)n * D + d] = hi;
    ol[(size_t)n * D + d] = lo;
}

// ---------------------------------------------------------------------------
// MFMA bf16x3 GEMM + fused attention dots. FT written as fp16 (gather dtype).
// MFMA issue grouped by 4 columns, pass-major (dep distance 4).
// HIST=true: blocks >= gemmBlocks run the CSR histogram pass instead (the
// atomic stream is latency-bound with ~0 VALU/LDS use -> hides under the
// MFMA/staging cycles of the co-resident GEMM blocks).
// ---------------------------------------------------------------------------
#define LDK 40

template <int NCOL, bool AFP32, bool HIST>
__global__ __launch_bounds__(256) void gemm_attn(
    const float* __restrict__ Xf, const unsigned short* __restrict__ Xhi,
    const unsigned short* __restrict__ Xlo, const unsigned short* __restrict__ Wthi,
    const unsigned short* __restrict__ Wtlo, const float* __restrict__ bias,
    const float* __restrict__ al, const float* __restrict__ bl,
    const float* __restrict__ ar, const float* __restrict__ br,
    _Float16* __restrict__ FT, float* __restrict__ A1, float* __restrict__ A2,
    int Nn, int D, const int* __restrict__ edst, int* __restrict__ cnt,
    int* __restrict__ pos, int E, int gemmBlocks) {
    if (HIST) {
        if ((int)blockIdx.x >= gemmBlocks) {
            int e = ((int)blockIdx.x - gemmBlocks) * 256 + threadIdx.x;
            if (e < E) pos[e] = atomicAdd(&cnt[edst[e]], 1);
            return;
        }
    }
    const int H = NCOL / 64;
    const int NC16 = NCOL / 16;
    __shared__ __align__(16) unsigned short Ahi_s[64 * LDK];
    __shared__ __align__(16) unsigned short Alo_s[64 * LDK];
    __shared__ __align__(16) unsigned short Bhi_s[NCOL * LDK];
    __shared__ __align__(16) unsigned short Blo_s[NCOL * LDK];

    int tid = threadIdx.x;
    int wv = tid >> 6, l = tid & 63, lm = l & 15, quad = l >> 4;
    int m0 = blockIdx.x * 64;

    f32x4 acc[NC16];
#pragma unroll
    for (int c = 0; c < NC16; c++) acc[c] = (f32x4){0.f, 0.f, 0.f, 0.f};

    for (int d0 = 0; d0 < D; d0 += 32) {
        if (AFP32) {
#pragma unroll
            for (int i = 0; i < 2; i++) {
                int u = tid + i * 256;
                int row = u >> 3, c4 = u & 7;
                float4 v = make_float4(0.f, 0.f, 0.f, 0.f);
                if (m0 + row < Nn)
                    v = *(const float4*)&Xf[(size_t)(m0 + row) * D + d0 + c4 * 4];
                float f[4] = {v.x, v.y, v.z, v.w};
                unsigned short hi[4], lo[4];
#pragma unroll
                for (int j = 0; j < 4; j++) {
                    hi[j] = bf16_rne(f[j]);
                    lo[j] = bf16_rne(f[j] - bf16_tof(hi[j]));
                }
                *(ushort4*)&Ahi_s[row * LDK + c4 * 4] = make_ushort4(hi[0], hi[1], hi[2], hi[3]);
                *(ushort4*)&Alo_s[row * LDK + c4 * 4] = make_ushort4(lo[0], lo[1], lo[2], lo[3]);
            }
        } else {
            int row = tid >> 2, q = tid & 3;
            u16x8 vh = (u16x8)0, vl = (u16x8)0;
            if (m0 + row < Nn) {
                vh = *(const u16x8*)&Xhi[(size_t)(m0 + row) * D + d0 + q * 8];
                vl = *(const u16x8*)&Xlo[(size_t)(m0 + row) * D + d0 + q * 8];
            }
            *(u16x8*)&Ahi_s[row * LDK + q * 8] = vh;
            *(u16x8*)&Alo_s[row * LDK + q * 8] = vl;
        }
#pragma unroll
        for (int i = 0; i < NCOL / 64; i++) {
            int u = tid + i * 256;
            int n = u >> 2, q = u & 3;
            *(u16x8*)&Bhi_s[n * LDK + q * 8] =
                *(const u16x8*)&Wthi[(size_t)n * D + d0 + q * 8];
            *(u16x8*)&Blo_s[n * LDK + q * 8] =
                *(const u16x8*)&Wtlo[(size_t)n * D + d0 + q * 8];
        }
        __syncthreads();

        int arow = wv * 16 + lm;
        bf16x8 ah = *(const bf16x8*)&Ahi_s[arow * LDK + quad * 8];
        bf16x8 alo = *(const bf16x8*)&Alo_s[arow * LDK + quad * 8];
#pragma unroll
        for (int cg = 0; cg < NC16; cg += 4) {
            bf16x8 bh4[4], bl4[4];
#pragma unroll
            for (int u = 0; u < 4; u++) {
                bh4[u] = *(const bf16x8*)&Bhi_s[((cg + u) * 16 + lm) * LDK + quad * 8];
                bl4[u] = *(const bf16x8*)&Blo_s[((cg + u) * 16 + lm) * LDK + quad * 8];
            }
#pragma unroll
            for (int u = 0; u < 4; u++)
                acc[cg + u] = __builtin_amdgcn_mfma_f32_16x16x32_bf16(ah, bh4[u], acc[cg + u], 0, 0, 0);
#pragma unroll
            for (int u = 0; u < 4; u++)
                acc[cg + u] = __builtin_amdgcn_mfma_f32_16x16x32_bf16(ah, bl4[u], acc[cg + u], 0, 0, 0);
#pragma unroll
            for (int u = 0; u < 4; u++)
                acc[cg + u] = __builtin_amdgcn_mfma_f32_16x16x32_bf16(alo, bh4[u], acc[cg + u], 0, 0, 0);
        }
        __syncthreads();
    }

    float bj[NC16], alj[NC16], arj[NC16];
#pragma unroll
    for (int c = 0; c < NC16; c++) {
        bj[c] = bias[c * 16 + lm];
        alj[c] = al[c * 16 + lm];
        arj[c] = ar[c * 16 + lm];
    }
#pragma unroll
    for (int reg = 0; reg < 4; reg++) {
        int row = m0 + wv * 16 + quad * 4 + reg;
        bool ok = row < Nn;
        float s1[H], s2[H];
#pragma unroll
        for (int h = 0; h < H; h++) { s1[h] = 0.f; s2[h] = 0.f; }
#pragma unroll
        for (int c = 0; c < NC16; c++) {
            float o = acc[c][reg] + bj[c];
            int h = c >> 2;
            s1[h] += o * alj[c];
            s2[h] += o * arj[c];
            if (ok) FT[(size_t)row * NCOL + c * 16 + lm] = (_Float16)o;
        }
#pragma unroll
        for (int h = 0; h < H; h++) {
#pragma unroll
            for (int d = 1; d < 16; d <<= 1) {
                s1[h] += __shfl_xor(s1[h], d);
                s2[h] += __shfl_xor(s2[h], d);
            }
        }
        if (ok && lm == 0) {
#pragma unroll
            for (int h = 0; h < H; h++) {
                A1[(size_t)row * H + h] = s1[h] + bl[h];
                A2[(size_t)row * H + h] = s2[h] + br[h];
            }
        }
    }
}

// ---------------------------------------------------------------------------
// Edge aggregation + ELU, one wave per dst node. Inline scores (no max:
// scores are O(+-10), exp safe in fp32; alpha identical to reference).
// Per-edge instruction diet: {sj,w} packed as int2 in LDS (1 ds_read_b64
// broadcast), 32-bit byte-offset gather addressing, v_fma_mix_f32 (no
// v_cvt). 16-deep batches, zero-weight padding (w=0 -> exact no-op).
// H=2: lane owns ft elems 2*lane, 2*lane+1; bf16 hi/lo output for next GEMM.
// ---------------------------------------------------------------------------
__global__ __launch_bounds__(256) void agg2_kernel(
    const _Float16* __restrict__ ft, const float* __restrict__ a1,
    const float* __restrict__ a2, const int* __restrict__ off,
    const int* __restrict__ esrc, unsigned short* __restrict__ ohi,
    unsigned short* __restrict__ olo, int Nn) {
    __shared__ __align__(16) int2 pk0s[4][64];
    __shared__ __align__(16) int2 pk1s[4][64];
    int wv = threadIdx.x >> 6, lane = threadIdx.x & 63;
    int n = blockIdx.x * 4 + wv;
    if (n >= Nn) return;
    int o0 = off[n], deg = off[n + 1] - o0;
    int hs = lane >> 5, cl2 = lane * 2;
    unsigned lb = (unsigned)lane * 4u;  // my byte offset within a 256B ft row
    if (deg == 0) {
        *(ushort2*)&ohi[(size_t)n * 128 + cl2] = make_ushort2(0, 0);
        *(ushort2*)&olo[(size_t)n * 128 + cl2] = make_ushort2(0, 0);
        return;
    }
    const char* ftb = (const char*)ft;
    const int2* pw = hs ? pk1s[wv] : pk0s[wv];
    float2 a1v = *(const float2*)&a1[(size_t)n * 2];
    float ax = 0.f, ay = 0.f;
    float ds0 = 0.f, ds1 = 0.f;
    for (int e0 = 0; e0 < deg; e0 += 64) {
        int nE = min(64, deg - e0);
        float w0 = 0.f, w1 = 0.f;
        int sj = 0;
        if (lane < nE) {
            sj = esrc[o0 + e0 + lane];
            float2 a2j = *(const float2*)((const char*)a2 + ((unsigned)sj << 3));
            float t0 = a1v.x + a2j.x;
            float t1 = a1v.y + a2j.y;
            t0 = t0 > 0.f ? t0 : NEG_SLOPE * t0;
            t1 = t1 > 0.f ? t1 : NEG_SLOPE * t1;
            w0 = __expf(t0);
            w1 = __expf(t1);
        }
        ds0 += w0;
        ds1 += w1;
        pk0s[wv][lane] = make_int2(sj, __float_as_int(w0));
        pk1s[wv][lane] = make_int2(sj, __float_as_int(w1));
        // wave-synchronous: DS ops in a wave execute in order, no barrier.
        // Slots >= nE carry w=0 (+0.0 no-op).
        int nB = (nE + 15) >> 4;
        for (int b = 0; b < nB; b++) {
            int j = b * 16;
            int2 pb[16];
#pragma unroll
            for (int u = 0; u < 16; u++) pb[u] = pw[j + u];
            unsigned f[16];
#pragma unroll
            for (int u = 0; u < 16; u++)
                f[u] = *(const unsigned*)(ftb + (((unsigned)pb[u].x << 8) + lb));
#pragma unroll
            for (int u = 0; u < 16; u++) {
                float w = __int_as_float(pb[u].y);
                fmamix_lo(ax, f[u], w);
                fmamix_hi(ay, f[u], w);
            }
        }
    }
#pragma unroll
    for (int d = 1; d < 64; d <<= 1) {
        ds0 += __shfl_xor(ds0, d);
        ds1 += __shfl_xor(ds1, d);
    }
    float rd = 1.f / (hs ? ds1 : ds0);
    float rx = ax * rd, ry = ay * rd;
    rx = rx > 0.f ? rx : expm1f(rx);
    ry = ry > 0.f ? ry : expm1f(ry);
    unsigned short hx = bf16_rne(rx), hy = bf16_rne(ry);
    unsigned short lx = bf16_rne(rx - bf16_tof(hx)), ly = bf16_rne(ry - bf16_tof(hy));
    *(ushort2*)&ohi[(size_t)n * 128 + cl2] = make_ushort2(hx, hy);
    *(ushort2*)&olo[(size_t)n * 128 + cl2] = make_ushort2(lx, ly);
}

// H=1: lane owns ft elem `lane` (fp16 gather, 128B rows); fp32 output.
__global__ __launch_bounds__(256) void agg1_kernel(
    const _Float16* __restrict__ ft, const float* __restrict__ a1,
    const float* __restrict__ a2, const int* __restrict__ off,
    const int* __restrict__ esrc, float* __restrict__ out, int Nn) {
    __shared__ __align__(16) int2 pks[4][64];
    int wv = threadIdx.x >> 6, lane = threadIdx.x & 63;
    int n = blockIdx.x * 4 + wv;
    if (n >= Nn) return;
    int o0 = off[n], deg = off[n + 1] - o0;
    if (deg == 0) {
        out[(size_t)n * 64 + lane] = 0.f;
        return;
    }
    const char* ftb = (const char*)ft;
    unsigned lb = (unsigned)lane * 2u;  // my byte offset within a 128B ft row
    float a1v = a1[n];
    float acc = 0.f, dsum = 0.f;
    for (int e0 = 0; e0 < deg; e0 += 64) {
        int nE = min(64, deg - e0);
        float wl = 0.f;
        int sj = 0;
        if (lane < nE) {
            sj = esrc[o0 + e0 + lane];
            float t = a1v + a2[sj];
            t = t > 0.f ? t : NEG_SLOPE * t;
            wl = __expf(t);
        }
        dsum += wl;
        pks[wv][lane] = make_int2(sj, __float_as_int(wl));
        int nB = (nE + 15) >> 4;
        for (int b = 0; b < nB; b++) {
            int j = b * 16;
            int2 pb[16];
#pragma unroll
            for (int u = 0; u < 16; u++) pb[u] = pks[wv][j + u];
            unsigned f[16];
#pragma unroll
            for (int u = 0; u < 16; u++)
                f[u] = *(const unsigned short*)(ftb + (((unsigned)pb[u].x << 7) + lb));
#pragma unroll
            for (int u = 0; u < 16; u++)
                fmamix_lo(acc, f[u], __int_as_float(pb[u].y));
        }
    }
#pragma unroll
    for (int d = 1; d < 64; d <<= 1) dsum += __shfl_xor(dsum, d);
    float r = acc / dsum;
    out[(size_t)n * 64 + lane] = r > 0.f ? r : expm1f(r);
}

// ---------------------------------------------------------------------------
// launch
// ---------------------------------------------------------------------------
extern "C" void kernel_launch(void* const* d_in, const int* in_sizes, int n_in,
                              void* d_out, int out_size, void* d_ws, size_t ws_size,
                              hipStream_t stream) {
    const float* features = (const float*)d_in[0];
    const int* src = (const int*)d_in[1];
    const int* dst = (const int*)d_in[2];
    const float* W0 = (const float*)d_in[3];
    const float* b0 = (const float*)d_in[4];
    const float* al0 = (const float*)d_in[5];
    const float* bl0 = (const float*)d_in[6];
    const float* ar0 = (const float*)d_in[7];
    const float* br0 = (const float*)d_in[8];
    const float* W1 = (const float*)d_in[9];
    const float* b1 = (const float*)d_in[10];
    const float* al1 = (const float*)d_in[11];
    const float* bl1 = (const float*)d_in[12];
    const float* ar1 = (const float*)d_in[13];
    const float* br1 = (const float*)d_in[14];
    const float* Wf = (const float*)d_in[15];
    const float* bf = (const float*)d_in[16];
    const float* alf = (const float*)d_in[17];
    const float* blf = (const float*)d_in[18];
    const float* arf = (const float*)d_in[19];
    const float* brf = (const float*)d_in[20];

    char* p = (char*)d_ws;
    auto carve = [&](size_t bytes) {
        void* q = (void*)p;
        p += (bytes + 255) & ~(size_t)255;
        return q;
    };
    _Float16* ft = (_Float16*)carve((size_t)NN * 128 * 2);
    unsigned short* Xhi = (unsigned short*)carve((size_t)NN * 128 * 2);
    unsigned short* Xlo = (unsigned short*)carve((size_t)NN * 128 * 2);
    float* a1 = (float*)carve((size_t)NN * 2 * 4);
    float* a2 = (float*)carve((size_t)NN * 2 * 4);
    int* off = (int*)carve((size_t)(NN + 1) * 4);
    int* cnt = (int*)carve((size_t)NN * 4);
    int* esrc = (int*)carve((size_t)EE * 4);
    int* pos = (int*)carve((size_t)EE * 4);
    int* aux = (int*)carve(64 * 4);
    unsigned short* w0h = (unsigned short*)carve(32768 * 2);
    unsigned short* w0l = (unsigned short*)carve(32768 * 2);
    unsigned short* w1h = (unsigned short*)carve(16384 * 2);
    unsigned short* w1l = (unsigned short*)carve(16384 * 2);
    unsigned short* wfh = (unsigned short*)carve(8192 * 2);
    unsigned short* wfl = (unsigned short*)carve(8192 * 2);

    const int NB_SCAN = (NN + 1023) / 1024;
    const int GE = (EE + 255) / 256;

    const int gx = (NN + 63) / 64;
    const int gn = (NN + 3) / 4;

    // ---- weight convert; cnt zero for the fused histogram ----
    hipMemsetAsync(cnt, 0, (size_t)NN * 4, stream);
    conv_w_kernel<<<(57344 + 255) / 256, 256, 0, stream>>>(W0, W1, Wf, w0h, w0l, w1h,
                                                           w1l, wfh, wfl);

    // ---- layer 0 GEMM fused with CSR histogram (independent work;
    //      the atomic stream hides under MFMA/staging cycles) ----
    gemm_attn<128, true, true><<<gx + GE, 256, 0, stream>>>(
        features, nullptr, nullptr, w0h, w0l, b0, al0, bl0, ar0, br0, ft, a1, a2,
        NN, DIN, dst, cnt, pos, EE, gx);

    // ---- finish CSR build ----
    scanA_kernel<<<NB_SCAN, 1024, 0, stream>>>(cnt, off, aux, NN);
    scanC_kernel<<<NB_SCAN, 1024, 0, stream>>>(aux, off, NN);
    scatter_kernel<<<GE, 256, 0, stream>>>(src, dst, off, pos, esrc, EE);

    agg2_kernel<<<gn, 256, 0, stream>>>(ft, a1, a2, off, esrc, Xhi, Xlo, NN);

    // ---- layer 1: D=128, H=2 (bf16 A) ----
    gemm_attn<128, false, false><<<gx, 256, 0, stream>>>(
        nullptr, Xhi, Xlo, w1h, w1l, b1, al1, bl1, ar1, br1, ft, a1, a2, NN, 128,
        nullptr, nullptr, nullptr, 0, 0);
    agg2_kernel<<<gn, 256, 0, stream>>>(ft, a1, a2, off, esrc, Xhi, Xlo, NN);

    // ---- final layer: D=128, H=1 ----
    gemm_attn<64, false, false><<<gx, 256, 0, stream>>>(
        nullptr, Xhi, Xlo, wfh, wfl, bf, alf, blf, arf, brf, ft, a1, a2, NN, 128,
        nullptr, nullptr, nullptr, 0, 0);
    agg1_kernel<<<gn, 256, 0, stream>>>(ft, a1, a2, off, esrc, (float*)d_out, NN);
}